// Round 1
// baseline (16204.376 us; speedup 1.0000x reference)
//
#include <hip/hip_runtime.h>
#include <stdint.h>
#include <stddef.h>

// Problem constants
constexpr int Bb = 16, Tt = 256, Vv = 32000, Ee = 512, Hh = 1024;
constexpr int M_TOK = Bb * Tt;  // 4096 tokens

using short8 = __attribute__((ext_vector_type(8))) short;
using f32x4v = __attribute__((ext_vector_type(4))) float;

__device__ __forceinline__ uint16_t f2bf(float f) {
    uint32_t u = __builtin_bit_cast(uint32_t, f);
    uint32_t r = (u + 0x7FFFu + ((u >> 16) & 1u)) >> 16;  // round-to-nearest-even
    return (uint16_t)r;
}

// ---------------- zero init (hbuf + cell state) ----------------
__global__ void k_zero(float* __restrict__ p, int n) {
    int i = blockIdx.x * 256 + threadIdx.x;
    if (i < n) p[i] = 0.f;
}

// ---------------- embedding gather -> bf16 ----------------
__global__ void k_embed(const int* __restrict__ ids, const float* __restrict__ emb,
                        uint16_t* __restrict__ x0) {
    int tid = blockIdx.x * 256 + threadIdx.x;     // over 4096*512
    int m = tid >> 9, e = tid & 511;
    x0[tid] = f2bf(emb[(size_t)ids[m] * Ee + e]);
}

// ---------------- fp32 (RxC) -> transposed dst (C x dstride), fp32 or bf16 ----------------
template<typename TD>
__global__ void k_transpose(const float* __restrict__ src, TD* __restrict__ dst,
                            int R, int C, int dstride, int dofs) {
    __shared__ float tile[32][33];
    int c0 = blockIdx.x * 32, r0 = blockIdx.y * 32;
    int tx = threadIdx.x, ty = threadIdx.y;       // 32 x 8
    #pragma unroll
    for (int k = 0; k < 32; k += 8)
        tile[ty + k][tx] = src[(size_t)(r0 + ty + k) * C + c0 + tx];
    __syncthreads();
    #pragma unroll
    for (int k = 0; k < 32; k += 8) {
        float v = tile[tx][ty + k];
        size_t di = (size_t)(c0 + ty + k) * dstride + dofs + r0 + tx;
        if constexpr (sizeof(TD) == 2) dst[di] = f2bf(v);
        else                           dst[di] = v;
    }
}

// ---------------- bf16 MFMA GEMM: C[M,N] = A[M,K] * Bt[N,K]^T + bias ----------------
// 128x128 block tile, BK=32, 4 waves (2x2), each wave 64x64 (4x4 frags of 16x16x32).
template<bool MASKED>
__global__ __launch_bounds__(256) void k_gemm_bt(
    const uint16_t* __restrict__ A, const uint16_t* __restrict__ Bt,
    const float* __restrict__ bias, float* __restrict__ Cmat,
    const int* __restrict__ ids, int M, int N, int K)
{
    __shared__ uint16_t As[128][40];   // +8 pad: 80B row stride -> 2-way banks (free)
    __shared__ uint16_t Bs[128][40];
    const int n0 = blockIdx.x * 128, m0 = blockIdx.y * 128;
    const int tid = threadIdx.x;
    const int wid = tid >> 6, lane = tid & 63;
    const int wm = (wid & 1) * 64, wn = (wid >> 1) * 64;
    const int fr = lane & 15, kq = lane >> 4;   // frag row (m/n), k-quad

    f32x4v acc[4][4] = {};
    for (int k0 = 0; k0 < K; k0 += 32) {
        #pragma unroll
        for (int rep = 0; rep < 2; ++rep) {
            int idx = tid + rep * 256;          // 0..511 : 128 rows x 4 k-chunks
            int row = idx >> 2, kc = (idx & 3) * 8;
            *(uint4*)&As[row][kc] = *(const uint4*)&A [(size_t)(m0 + row) * K + k0 + kc];
            *(uint4*)&Bs[row][kc] = *(const uint4*)&Bt[(size_t)(n0 + row) * K + k0 + kc];
        }
        __syncthreads();
        short8 af[4], bf[4];
        #pragma unroll
        for (int i = 0; i < 4; ++i) af[i] = *(const short8*)&As[wm + i * 16 + fr][kq * 8];
        #pragma unroll
        for (int j = 0; j < 4; ++j) bf[j] = *(const short8*)&Bs[wn + j * 16 + fr][kq * 8];
        #pragma unroll
        for (int i = 0; i < 4; ++i)
            #pragma unroll
            for (int j = 0; j < 4; ++j)
                acc[i][j] = __builtin_amdgcn_mfma_f32_16x16x32_bf16(af[i], bf[j], acc[i][j], 0, 0, 0);
        __syncthreads();
    }
    // epilogue: D lane l reg r -> row=(l>>4)*4+r, col=l&15
    #pragma unroll
    for (int i = 0; i < 4; ++i) {
        #pragma unroll
        for (int r = 0; r < 4; ++r) {
            int row = m0 + wm + i * 16 + kq * 4 + r;
            bool dead = MASKED && (ids[row] == 0);
            #pragma unroll
            for (int j = 0; j < 4; ++j) {
                int col = n0 + wn + j * 16 + fr;
                float v = acc[i][j][r] + bias[col];
                if (MASKED && dead) v = (col == 0) ? 1.0f : 0.0f;
                Cmat[(size_t)row * N + col] = v;
            }
        }
    }
}

// ---------------- pipelined LSTM step ----------------
// Launch t = 0..256. Layer0 (blocks with blockIdx&1==0) does step t (if t<256).
// Layer1 (blockIdx&1==1) does step u=t-1 (if t>=1), reading h0(t-1) & h1(t-2)
// from hbuf slot (t&1); both layers write slot (t&1)^1.
// hbuf layout: [2][16][2048] fp32, per-b vector = [h0(1024); h1(1024)].
__global__ __launch_bounds__(256) void k_step(
    int t, const int* __restrict__ ids, const float* __restrict__ xz0,
    const float* __restrict__ W0T, const float* __restrict__ W1T,
    const float* __restrict__ b1v, float* __restrict__ hbuf,
    float* __restrict__ cbuf, uint16_t* __restrict__ hs1)
{
    const int layer = blockIdx.x & 1;
    const int chunk = blockIdx.x >> 1;            // 0..255 -> 4 cells each
    const int step = layer ? (t - 1) : t;
    if (step < 0 || step >= Tt) return;
    const int K = layer ? 2048 : 1024;
    const float* __restrict__ WT = layer ? W1T : W0T;
    const int j0 = chunk * 4;
    const int tid = threadIdx.x;
    const int b = tid & 15, jl = (tid >> 4) & 3, s = tid >> 6;

    const int cur = t & 1, nxt = cur ^ 1;
    const float* __restrict__ xv = hbuf + (size_t)cur * (Bb * 2048) + b * 2048;

    const int klen = K >> 2;
    const int kb = s * klen;
    float acc0 = 0.f, acc1 = 0.f, acc2 = 0.f, acc3 = 0.f;
    const float* __restrict__ w0 = WT + (size_t)(j0 + jl + 0 * Hh) * K;
    const float* __restrict__ w1 = WT + (size_t)(j0 + jl + 1 * Hh) * K;
    const float* __restrict__ w2 = WT + (size_t)(j0 + jl + 2 * Hh) * K;
    const float* __restrict__ w3 = WT + (size_t)(j0 + jl + 3 * Hh) * K;
    #pragma unroll 4
    for (int k = kb; k < kb + klen; k += 4) {
        float4 x = *(const float4*)&xv[k];
        float4 a = *(const float4*)&w0[k];
        float4 c = *(const float4*)&w1[k];
        float4 d = *(const float4*)&w2[k];
        float4 e = *(const float4*)&w3[k];
        acc0 += x.x * a.x + x.y * a.y + x.z * a.z + x.w * a.w;
        acc1 += x.x * c.x + x.y * c.y + x.z * c.z + x.w * c.w;
        acc2 += x.x * d.x + x.y * d.y + x.z * d.z + x.w * d.w;
        acc3 += x.x * e.x + x.y * e.y + x.z * e.z + x.w * e.w;
    }
    __shared__ float part[4][16][4][4];
    part[s][b][jl][0] = acc0;
    part[s][b][jl][1] = acc1;
    part[s][b][jl][2] = acc2;
    part[s][b][jl][3] = acc3;
    __syncthreads();

    if (tid < 64) {
        const int b2 = tid & 15, j2 = tid >> 4;   // j2: 0..3
        const int j = j0 + j2;
        const int m = b2 * Tt + step;
        float z[4];
        #pragma unroll
        for (int g = 0; g < 4; ++g) {
            float base = layer ? b1v[j + g * Hh]
                               : xz0[(size_t)m * 4096 + j + g * Hh];
            z[g] = base + part[0][b2][j2][g] + part[1][b2][j2][g]
                        + part[2][b2][j2][g] + part[3][b2][j2][g];
        }
        float* cptr = cbuf + (size_t)layer * (Bb * Hh) + b2 * Hh + j;
        float c = *cptr;
        float ig = 1.f / (1.f + __expf(-z[0]));
        float fg = 1.f / (1.f + __expf(-z[1]));
        float gg = tanhf(z[2]);
        float og = 1.f / (1.f + __expf(-z[3]));
        float cn = fg * c + ig * gg;
        float hn = og * tanhf(cn);
        bool msk = ids[m] != 0;
        const int off = layer * Hh;
        float hprev = hbuf[(size_t)cur * (Bb * 2048) + b2 * 2048 + off + j];
        float h2 = msk ? hn : hprev;
        float c2 = msk ? cn : c;
        *cptr = c2;
        hbuf[(size_t)nxt * (Bb * 2048) + b2 * 2048 + off + j] = h2;
        if (layer) hs1[(size_t)m * Hh + j] = f2bf(h2);
    }
}

// ---------------- launcher ----------------
extern "C" void kernel_launch(void* const* d_in, const int* in_sizes, int n_in,
                              void* d_out, int out_size, void* d_ws, size_t ws_size,
                              hipStream_t stream) {
    const int*   ids  = (const int*)  d_in[0];
    const float* emb  = (const float*)d_in[1];
    const float* Wk0  = (const float*)d_in[2];
    const float* Wr0  = (const float*)d_in[3];
    const float* b0   = (const float*)d_in[4];
    const float* Wk1  = (const float*)d_in[5];
    const float* Wr1  = (const float*)d_in[6];
    const float* b1   = (const float*)d_in[7];
    const float* Wout = (const float*)d_in[8];
    const float* bout = (const float*)d_in[9];
    float* out = (float*)d_out;

    char* ws = (char*)d_ws;
    size_t off = 0;
    auto alloc = [&](size_t bytes) -> void* {
        void* p = ws + off;
        off += (bytes + 255) & ~(size_t)255;
        return p;
    };
    // hbuf + cbuf adjacent so one zero-pass covers both
    float*    hbuf  = (float*)   alloc(2 * Bb * 2048 * 4);       // 256 KiB
    float*    cbuf  = (float*)   alloc(2 * Bb * Hh * 4);         // 128 KiB
    uint16_t* x0bf  = (uint16_t*)alloc((size_t)M_TOK * Ee * 2);  // 4 MiB
    uint16_t* WkT0  = (uint16_t*)alloc((size_t)4096 * Ee * 2);   // 4 MiB
    float*    W0T   = (float*)   alloc((size_t)4096 * Hh * 4);   // 16 MiB
    float*    W1T   = (float*)   alloc((size_t)4096 * 2048 * 4); // 32 MiB
    uint16_t* WoutT = (uint16_t*)alloc((size_t)Vv * Hh * 2);     // 62.5 MiB
    float*    xz0   = (float*)   alloc((size_t)M_TOK * 4096 * 4);// 64 MiB
    uint16_t* hs1   = (uint16_t*)alloc((size_t)M_TOK * Hh * 2);  // 8 MiB

    // 1) zero h/c state (ws is poisoned 0xAA before every timed call)
    k_zero<<<dim3((2 * Bb * 2048 + 2 * Bb * Hh + 255) / 256), dim3(256), 0, stream>>>(
        hbuf, 2 * Bb * 2048 + 2 * Bb * Hh);

    // 2) embedding gather -> bf16
    k_embed<<<dim3(M_TOK * Ee / 256), dim3(256), 0, stream>>>(ids, emb, x0bf);

    // 3) weight transposes (K-contiguous layouts)
    k_transpose<uint16_t><<<dim3(4096 / 32, Ee / 32),  dim3(32, 8), 0, stream>>>(Wk0, WkT0, Ee, 4096, Ee, 0);
    k_transpose<float>   <<<dim3(4096 / 32, Hh / 32),  dim3(32, 8), 0, stream>>>(Wr0, W0T, Hh, 4096, Hh, 0);
    k_transpose<float>   <<<dim3(4096 / 32, Hh / 32),  dim3(32, 8), 0, stream>>>(Wk1, W1T, Hh, 4096, 2048, 0);
    k_transpose<float>   <<<dim3(4096 / 32, Hh / 32),  dim3(32, 8), 0, stream>>>(Wr1, W1T, Hh, 4096, 2048, Hh);
    k_transpose<uint16_t><<<dim3(Vv / 32,   Hh / 32),  dim3(32, 8), 0, stream>>>(Wout, WoutT, Hh, Vv, Hh, 0);

    // 4) xz0 = x0 @ Wk0 + b0   (M=4096, N=4096, K=512)
    k_gemm_bt<false><<<dim3(4096 / 128, M_TOK / 128), dim3(256), 0, stream>>>(
        x0bf, WkT0, b0, xz0, nullptr, M_TOK, 4096, Ee);

    // 5) pipelined 2-layer recurrence: 257 launches
    for (int t = 0; t <= Tt; ++t)
        k_step<<<dim3(512), dim3(256), 0, stream>>>(t, ids, xz0, W0T, W1T, b1, hbuf, cbuf, hs1);

    // 6) logits = hs1 @ W_out + b_out, with mask/one-hot epilogue
    k_gemm_bt<true><<<dim3(Vv / 128, M_TOK / 128), dim3(256), 0, stream>>>(
        hs1, WoutT, bout, out, ids, M_TOK, Vv, Hh);
}